// Round 2
// baseline (27.246 us; speedup 1.0000x reference)
//
#include <hip/hip_runtime.h>

// Potts model: out[b] = sum_t coeffs[t] * (x[b,idx[t,0..3]] all equal)
// B=2048, N=4096, T=8192, K=4, states are exact floats in {0.0,1.0,2.0}.
//
// v2: 2-bit state packing. Block owns G=8 rows; xs[n] is a u16 whose bits
// [2g+1:2g] encode row g's state at column n ((bits>>29)&3 is injective on
// {0.0f,1.0f,2.0f}). Gathers are ds_read_u16 (1 bank/lane, ~conflict-free
// vs round-1's 2-bank ds_read_b64). idx/coeffs preloaded to registers
// before the staging barrier to hide their latency under the x stream.

#define NN 4096
#define TT 8192
#define G 8
#define THREADS 512
#define TPT (TT / THREADS)   // 16 t's per thread

typedef unsigned long long u64;
typedef unsigned int u32;
typedef unsigned short u16;

__device__ __forceinline__ u32 code2(float f) {
    // {0x00000000, 0x3F800000, 0x40000000} >> 29 & 3  ->  {0, 1, 2}
    return (__float_as_uint(f) >> 29) & 3u;
}

__global__ __launch_bounds__(THREADS) void potts_kernel(
    const float* __restrict__ x,
    const float* __restrict__ coeffs,
    const int*   __restrict__ idx,
    float*       __restrict__ out)
{
    __shared__ u16 xs[NN];                 // 8 KB
    __shared__ float red[THREADS / 64][G];

    const int tid = threadIdx.x;
    const int b0  = blockIdx.x * G;

    // Preload this thread's idx/coeff slice (latency hidden under staging).
    int4  ii[TPT];
    float cf[TPT];
    #pragma unroll
    for (int i = 0; i < TPT; ++i) {
        const int t = tid + i * THREADS;
        ii[i] = *reinterpret_cast<const int4*>(idx + 4 * t);
        cf[i] = coeffs[t];
    }

    // Stage G rows, 2-bit packed. Each thread packs 4 consecutive columns
    // (float4 per row) into 4 u16s = one aligned ds_write_b64.
    for (int c = tid; c < NN / 4; c += THREADS) {
        const int n0 = c * 4;
        u64 v = 0;
        #pragma unroll
        for (int g = 0; g < G; ++g) {
            const float4 f =
                *reinterpret_cast<const float4*>(x + (size_t)(b0 + g) * NN + n0);
            v |= (u64)(code2(f.x) << (2 * g));
            v |= (u64)(code2(f.y) << (2 * g)) << 16;
            v |= (u64)(code2(f.z) << (2 * g)) << 32;
            v |= (u64)(code2(f.w) << (2 * g)) << 48;
        }
        reinterpret_cast<u64*>(xs)[c] = v;
    }
    __syncthreads();

    float acc[G];
    #pragma unroll
    for (int g = 0; g < G; ++g) acc[g] = 0.f;

    #pragma unroll 4
    for (int i = 0; i < TPT; ++i) {
        const u32 a = xs[ii[i].x];
        const u32 b = xs[ii[i].y];
        const u32 c = xs[ii[i].z];
        const u32 d = xs[ii[i].w];
        const u32 diff = (a ^ b) | (a ^ c) | (a ^ d);
        const u32 m = diff | (diff >> 1);   // bit 2g clear <=> clique g equal
        const float cv = cf[i];
        #pragma unroll
        for (int g = 0; g < G; ++g)
            acc[g] += ((m >> (2 * g)) & 1u) ? 0.f : cv;
    }

    // Block reduction: wave shuffle, then tiny LDS reduce.
    #pragma unroll
    for (int g = 0; g < G; ++g) {
        float v = acc[g];
        #pragma unroll
        for (int off = 32; off > 0; off >>= 1) v += __shfl_down(v, off, 64);
        if ((tid & 63) == 0) red[tid >> 6][g] = v;
    }
    __syncthreads();

    if (tid < G) {
        float s = 0.f;
        #pragma unroll
        for (int w = 0; w < THREADS / 64; ++w) s += red[w][tid];
        out[b0 + tid] = s;
    }
}

extern "C" void kernel_launch(void* const* d_in, const int* in_sizes, int n_in,
                              void* d_out, int out_size, void* d_ws, size_t ws_size,
                              hipStream_t stream) {
    const float* x      = (const float*)d_in[0];   // [B, N] f32
    const float* coeffs = (const float*)d_in[1];   // [T] f32
    const int*   idx    = (const int*)d_in[2];     // [T, 4] i32

    float* out = (float*)d_out;                    // [B] f32

    const int Bn   = in_sizes[0] / NN;             // 2048
    const int grid = Bn / G;                       // 256 blocks, 1/CU

    potts_kernel<<<grid, THREADS, 0, stream>>>(x, coeffs, idx, out);
}

// Round 3
// 14.245 us; speedup vs baseline: 1.9126x; 1.9126x over previous
//
#include <hip/hip_runtime.h>

// Potts model: out[b] = sum_t coeffs[t] * (x[b,idx[t,0..3]] all equal)
// B=2048, N=4096, T=8192, K=4, states are exact floats in {0.0,1.0,2.0}.
//
// v3: same as v2 (2-bit state packing, u16 gathers) but the t-loop is FULLY
// unrolled so the preloaded ii[]/cf[] arrays are statically indexed and live
// in VGPRs. v2's "#pragma unroll 4" was a partial unroll -> runtime index ->
// arrays demoted to scratch (rule #20), causing the 27us regression.

#define NN 4096
#define TT 8192
#define G 8
#define THREADS 512
#define TPT (TT / THREADS)   // 16 t's per thread (compile-time)

typedef unsigned long long u64;
typedef unsigned int u32;
typedef unsigned short u16;

__device__ __forceinline__ u32 code2(float f) {
    // {0x00000000, 0x3F800000, 0x40000000} >> 29 & 3  ->  {0, 1, 2}
    return (__float_as_uint(f) >> 29) & 3u;
}

__global__ __launch_bounds__(THREADS) void potts_kernel(
    const float* __restrict__ x,
    const float* __restrict__ coeffs,
    const int*   __restrict__ idx,
    float*       __restrict__ out)
{
    __shared__ u16 xs[NN];                 // 8 KB
    __shared__ float red[THREADS / 64][G];

    const int tid = threadIdx.x;
    const int b0  = blockIdx.x * G;

    // Preload this thread's idx/coeff slice (latency hidden under staging).
    // Fully unrolled + statically indexed -> stays in VGPRs.
    int4  ii[TPT];
    float cf[TPT];
    #pragma unroll
    for (int i = 0; i < TPT; ++i) {
        const int t = tid + i * THREADS;
        ii[i] = *reinterpret_cast<const int4*>(idx + 4 * t);
        cf[i] = coeffs[t];
    }

    // Stage G rows, 2-bit packed. Each thread packs 4 consecutive columns
    // (float4 per row) into 4 u16s = one aligned ds_write_b64.
    #pragma unroll
    for (int k = 0; k < NN / 4 / THREADS; ++k) {
        const int c  = tid + k * THREADS;
        const int n0 = c * 4;
        u64 v = 0;
        #pragma unroll
        for (int g = 0; g < G; ++g) {
            const float4 f =
                *reinterpret_cast<const float4*>(x + (size_t)(b0 + g) * NN + n0);
            v |= (u64)(code2(f.x) << (2 * g));
            v |= (u64)(code2(f.y) << (2 * g)) << 16;
            v |= (u64)(code2(f.z) << (2 * g)) << 32;
            v |= (u64)(code2(f.w) << (2 * g)) << 48;
        }
        reinterpret_cast<u64*>(xs)[c] = v;
    }
    __syncthreads();

    float acc[G];
    #pragma unroll
    for (int g = 0; g < G; ++g) acc[g] = 0.f;

    #pragma unroll            // FULL unroll: static ii[i]/cf[i] indices
    for (int i = 0; i < TPT; ++i) {
        const u32 a = xs[ii[i].x];
        const u32 b = xs[ii[i].y];
        const u32 c = xs[ii[i].z];
        const u32 d = xs[ii[i].w];
        const u32 diff = (a ^ b) | (a ^ c) | (a ^ d);
        const u32 m = diff | (diff >> 1);   // bit 2g set <=> clique g differs
        const float cv = cf[i];
        #pragma unroll
        for (int g = 0; g < G; ++g)
            acc[g] += ((m >> (2 * g)) & 1u) ? 0.f : cv;
    }

    // Block reduction: wave shuffle, then tiny LDS reduce.
    #pragma unroll
    for (int g = 0; g < G; ++g) {
        float v = acc[g];
        #pragma unroll
        for (int off = 32; off > 0; off >>= 1) v += __shfl_down(v, off, 64);
        if ((tid & 63) == 0) red[tid >> 6][g] = v;
    }
    __syncthreads();

    if (tid < G) {
        float s = 0.f;
        #pragma unroll
        for (int w = 0; w < THREADS / 64; ++w) s += red[w][tid];
        out[b0 + tid] = s;
    }
}

extern "C" void kernel_launch(void* const* d_in, const int* in_sizes, int n_in,
                              void* d_out, int out_size, void* d_ws, size_t ws_size,
                              hipStream_t stream) {
    const float* x      = (const float*)d_in[0];   // [B, N] f32
    const float* coeffs = (const float*)d_in[1];   // [T] f32
    const int*   idx    = (const int*)d_in[2];     // [T, 4] i32

    float* out = (float*)d_out;                    // [B] f32

    const int Bn   = in_sizes[0] / NN;             // 2048
    const int grid = Bn / G;                       // 256 blocks, 1/CU

    potts_kernel<<<grid, THREADS, 0, stream>>>(x, coeffs, idx, out);
}